// Round 1
// baseline (123.726 us; speedup 1.0000x reference)
//
#include <hip/hip_runtime.h>

#define NE 8     // experts
#define TOPK 2

struct TokGate { float w0, w1; int g0, g1; };

// ---------------- Kernel 1: gating ----------------
// One wave (64 lanes) per token. Computes logits x[t]·gate_w[e], softmax,
// top-2, normalized weights. Writes per-token gate record to ws, gate indices
// (as float) to d_out, and accumulates per-expert prob sums + counts via
// block-level LDS reduction -> 8 global atomics per block.
__global__ void gate_kernel(const float* __restrict__ x,
                            const float* __restrict__ gate_w,
                            float* __restrict__ prob_sum,   // [NE] in ws (zeroed)
                            int* __restrict__ cnt,          // [NE] in ws (zeroed)
                            TokGate* __restrict__ tok,      // [T] in ws
                            float* __restrict__ gate_out,   // [T*2] in d_out
                            int T, int D) {
    __shared__ float s_psum[NE];
    __shared__ int   s_cnt[NE];
    int tid = threadIdx.x;
    if (tid < NE) { s_psum[tid] = 0.f; s_cnt[tid] = 0; }
    __syncthreads();

    int wave = tid >> 6;
    int lane = tid & 63;
    int t = blockIdx.x * (blockDim.x >> 6) + wave;
    if (t < T) {
        float acc[NE];
#pragma unroll
        for (int e = 0; e < NE; ++e) acc[e] = 0.f;
        const float* xt = x + (size_t)t * D;
        for (int d = lane; d < D; d += 64) {       // coalesced x read
            float xv = xt[d];
#pragma unroll
            for (int e = 0; e < NE; ++e)
                acc[e] = fmaf(xv, gate_w[e * D + d], acc[e]);   // gate_w L1-hit
        }
#pragma unroll
        for (int e = 0; e < NE; ++e) {
#pragma unroll
            for (int off = 32; off > 0; off >>= 1)
                acc[e] += __shfl_xor(acc[e], off);
        }
        // softmax over 8 (all lanes redundantly)
        float mx = acc[0];
#pragma unroll
        for (int e = 1; e < NE; ++e) mx = fmaxf(mx, acc[e]);
        float p[NE]; float s = 0.f;
#pragma unroll
        for (int e = 0; e < NE; ++e) { p[e] = expf(acc[e] - mx); s += p[e]; }
        float inv = 1.f / s;
#pragma unroll
        for (int e = 0; e < NE; ++e) p[e] *= inv;

        // top-2, first-index tie-break (matches jax.lax.top_k)
        int g0 = 0;
#pragma unroll
        for (int e = 1; e < NE; ++e) if (p[e] > p[g0]) g0 = e;
        int g1 = (g0 == 0) ? 1 : 0;
#pragma unroll
        for (int e = 0; e < NE; ++e) if (e != g0 && p[e] > p[g1]) g1 = e;

        float v0 = p[g0], v1 = p[g1];
        float wsum = v0 + v1;
        if (lane == 0) {
            TokGate tg;
            tg.w0 = v0 / wsum; tg.w1 = v1 / wsum;
            tg.g0 = g0; tg.g1 = g1;
            tok[t] = tg;
            gate_out[t * 2 + 0] = (float)g0;
            gate_out[t * 2 + 1] = (float)g1;
            atomicAdd(&s_cnt[g0], 1);
            atomicAdd(&s_cnt[g1], 1);
        }
        if (lane < NE) atomicAdd(&s_psum[lane], p[lane]);
    }
    __syncthreads();
    if (tid < NE) {
        atomicAdd(&prob_sum[tid], s_psum[tid]);
        atomicAdd(&cnt[tid], s_cnt[tid]);
    }
}

// ---------------- Kernel 2: losses ----------------
__global__ void loss_kernel(const float* __restrict__ prob_sum,
                            const int* __restrict__ cnt,
                            float* __restrict__ out_bal,
                            float* __restrict__ out_imp,
                            float* __restrict__ out_load,
                            int T) {
    int lane = threadIdx.x & 63;
    float ps = (lane < NE) ? prob_sum[lane] : 0.f;
    float cv = (lane < NE) ? (float)cnt[lane] : 0.f;
    float sum_ps = ps, sum_c = cv;
#pragma unroll
    for (int off = 4; off >= 1; off >>= 1) {   // reduce within 8-lane group
        sum_ps += __shfl_xor(sum_ps, off);
        sum_c  += __shfl_xor(sum_c, off);
    }
    float mean = sum_ps * (1.f / NE);
    float bal_term = 0.f, dev = 0.f;
    if (lane < NE) {
        bal_term = (ps / (float)T) * (cv / sum_c);
        float d = ps - mean;
        dev = d * d;
    }
#pragma unroll
    for (int off = 4; off >= 1; off >>= 1) {
        bal_term += __shfl_xor(bal_term, off);
        dev      += __shfl_xor(dev, off);
    }
    if (lane == 0) {
        *out_bal = (float)NE * bal_term;
        float var = dev / (float)(NE - 1);     // ddof=1
        *out_imp = var / (mean * mean);
    }
    if (lane < NE) out_load[lane] = cv;        // gate_load as float
}

// ---------------- Kernel 3: combine (the 402 MB write) ----------------
// out[t,:,:] = w0 * cand[g0,:,:] + w1 * cand[g1,:,:]; float4 everywhere.
__global__ void combine_kernel(const float4* __restrict__ cand,
                               const TokGate* __restrict__ tok,
                               float4* __restrict__ out,
                               int V /* Nq*D/4 */) {
    int t = blockIdx.x;
    TokGate tg = tok[t];
    const float4* c0 = cand + (size_t)tg.g0 * V;
    const float4* c1 = cand + (size_t)tg.g1 * V;
    float4* o = out + (size_t)t * V;
    float w0 = tg.w0, w1 = tg.w1;
    for (int i = threadIdx.x; i < V; i += blockDim.x) {
        float4 a = c0[i];
        float4 b = c1[i];
        float4 r;
        r.x = w0 * a.x + w1 * b.x;
        r.y = w0 * a.y + w1 * b.y;
        r.z = w0 * a.z + w1 * b.z;
        r.w = w0 * a.w + w1 * b.w;
        o[i] = r;
    }
}

extern "C" void kernel_launch(void* const* d_in, const int* in_sizes, int n_in,
                              void* d_out, int out_size, void* d_ws, size_t ws_size,
                              hipStream_t stream) {
    const float* x      = (const float*)d_in[0];   // [B,S,D]
    const float* gate_w = (const float*)d_in[1];   // [E,D]
    const float* cand   = (const float*)d_in[2];   // [E,Nq,D]

    const int E  = NE;
    const int D  = in_sizes[1] / E;          // 768
    const int T  = in_sizes[0] / D;          // 4096
    const int Nq = in_sizes[2] / (E * D);    // 32

    float* outf = (float*)d_out;
    size_t OUT_N = (size_t)T * Nq * D;
    float* out_bal  = outf + OUT_N;
    float* out_imp  = out_bal + 1;
    float* out_load = out_imp + 1;
    float* gate_out = out_load + E;

    float*   prob_sum = (float*)d_ws;                    // 32 B
    int*     cnt      = (int*)((char*)d_ws + 32);        // 32 B
    TokGate* tok      = (TokGate*)((char*)d_ws + 64);    // 16*T B

    // zero the accumulators each call (ws is poisoned once, never re-poisoned)
    hipMemsetAsync(d_ws, 0, 64, stream);

    gate_kernel<<<(T + 3) / 4, 256, 0, stream>>>(x, gate_w, prob_sum, cnt, tok,
                                                 gate_out, T, D);
    loss_kernel<<<1, 64, 0, stream>>>(prob_sum, cnt, out_bal, out_imp, out_load, T);

    int V = Nq * D / 4;   // 6144 float4 per token
    combine_kernel<<<T, 256, 0, stream>>>((const float4*)cand, tok,
                                          (float4*)d_out, V);
}

// Round 2
// 118.535 us; speedup vs baseline: 1.0438x; 1.0438x over previous
//
#include <hip/hip_runtime.h>

#define NE 8     // experts
#define TOPK 2

typedef float f4 __attribute__((ext_vector_type(4)));

struct TokGate { float w0, w1; int g0, g1; };

// ---------------- Kernel 1: gating ----------------
// One wave (64 lanes) per token. float4 dot products, no runtime register
// indexing (everything static-unrolled -> no scratch).
__global__ void gate_kernel(const f4* __restrict__ x,
                            const f4* __restrict__ gate_w,
                            float* __restrict__ prob_sum,   // [NE] ws (zeroed)
                            int* __restrict__ cnt,          // [NE] ws (zeroed)
                            TokGate* __restrict__ tok,      // [T] ws
                            float* __restrict__ gate_out,   // [T*2] d_out
                            int T, int D4 /* D/4 */) {
    __shared__ float s_psum[NE];
    __shared__ int   s_cnt[NE];
    int tid = threadIdx.x;
    if (tid < NE) { s_psum[tid] = 0.f; s_cnt[tid] = 0; }
    __syncthreads();

    int wave = tid >> 6;
    int lane = tid & 63;
    int t = blockIdx.x * (blockDim.x >> 6) + wave;
    if (t < T) {
        float acc[NE];
#pragma unroll
        for (int e = 0; e < NE; ++e) acc[e] = 0.f;
        const f4* xt = x + (size_t)t * D4;
        for (int d = lane; d < D4; d += 64) {      // coalesced 16B/lane
            f4 xv = xt[d];
#pragma unroll
            for (int e = 0; e < NE; ++e) {
                f4 gw = gate_w[e * D4 + d];        // L1-hit (24 KB total)
                acc[e] = fmaf(xv.x, gw.x,
                         fmaf(xv.y, gw.y,
                         fmaf(xv.z, gw.z,
                         fmaf(xv.w, gw.w, acc[e]))));
            }
        }
#pragma unroll
        for (int e = 0; e < NE; ++e) {
#pragma unroll
            for (int off = 32; off > 0; off >>= 1)
                acc[e] += __shfl_xor(acc[e], off);
        }
        // softmax over 8 (all lanes redundantly)
        float mx = acc[0];
#pragma unroll
        for (int e = 1; e < NE; ++e) mx = fmaxf(mx, acc[e]);
        float p[NE]; float s = 0.f;
#pragma unroll
        for (int e = 0; e < NE; ++e) { p[e] = expf(acc[e] - mx); s += p[e]; }
        float inv = 1.f / s;
#pragma unroll
        for (int e = 0; e < NE; ++e) p[e] *= inv;

        // top-2 with first-index tie-break; static indexing only
        float v0 = -1.f; int g0 = 0;
#pragma unroll
        for (int e = 0; e < NE; ++e)
            if (p[e] > v0) { v0 = p[e]; g0 = e; }
        float v1 = -1.f; int g1 = 0;
#pragma unroll
        for (int e = 0; e < NE; ++e)
            if (e != g0 && p[e] > v1) { v1 = p[e]; g1 = e; }

        float wsum = v0 + v1;
        if (lane == 0) {
            TokGate tg;
            tg.w0 = v0 / wsum; tg.w1 = v1 / wsum;
            tg.g0 = g0; tg.g1 = g1;
            tok[t] = tg;
            gate_out[t * 2 + 0] = (float)g0;
            gate_out[t * 2 + 1] = (float)g1;
            atomicAdd(&s_cnt[g0], 1);
            atomicAdd(&s_cnt[g1], 1);
        }
        // lane e contributes p[e]; select statically (cndmask chain, no scratch)
        float myp = 0.f;
#pragma unroll
        for (int e = 0; e < NE; ++e)
            if (lane == e) myp = p[e];
        if (lane < NE) atomicAdd(&s_psum[lane], myp);
    }
    __syncthreads();
    if (tid < NE) {
        atomicAdd(&prob_sum[tid], s_psum[tid]);
        atomicAdd(&cnt[tid], s_cnt[tid]);
    }
}

// ---------------- Kernel 2: losses ----------------
__global__ void loss_kernel(const float* __restrict__ prob_sum,
                            const int* __restrict__ cnt,
                            float* __restrict__ out_bal,
                            float* __restrict__ out_imp,
                            float* __restrict__ out_load,
                            int T) {
    int lane = threadIdx.x & 63;
    float ps = (lane < NE) ? prob_sum[lane] : 0.f;
    float cv = (lane < NE) ? (float)cnt[lane] : 0.f;
    float sum_ps = ps, sum_c = cv;
#pragma unroll
    for (int off = 4; off >= 1; off >>= 1) {
        sum_ps += __shfl_xor(sum_ps, off);
        sum_c  += __shfl_xor(sum_c, off);
    }
    float mean = sum_ps * (1.f / NE);
    float bal_term = 0.f, dev = 0.f;
    if (lane < NE) {
        bal_term = (ps / (float)T) * (cv / sum_c);
        float d = ps - mean;
        dev = d * d;
    }
#pragma unroll
    for (int off = 4; off >= 1; off >>= 1) {
        bal_term += __shfl_xor(bal_term, off);
        dev      += __shfl_xor(dev, off);
    }
    if (lane == 0) {
        *out_bal = (float)NE * bal_term;
        float var = dev / (float)(NE - 1);     // ddof=1
        *out_imp = var / (mean * mean);
    }
    if (lane < NE) out_load[lane] = cv;        // gate_load as float
}

// ---------------- Kernel 3: combine (402 MB nt-write) ----------------
// out[t] = w0*cand[g0] + w1*cand[g1]. Nontemporal stores keep the write
// stream out of L2 so cand (786 KB) stays L2-resident.
__global__ void combine_kernel(const f4* __restrict__ cand,
                               const TokGate* __restrict__ tok,
                               f4* __restrict__ out,
                               int V /* Nq*D/4 */) {
    int t = blockIdx.x;
    TokGate tg = tok[t];
    const f4* c0 = cand + (size_t)tg.g0 * V;
    const f4* c1 = cand + (size_t)tg.g1 * V;
    f4* o = out + (size_t)t * V;
    float w0 = tg.w0, w1 = tg.w1;
    int stride = blockDim.x;
    int i = threadIdx.x;
    // unroll-by-4 main loop (V=6144, stride=256 -> exactly 6 iterations)
    for (; i + 3 * stride < V; i += 4 * stride) {
        f4 a0 = c0[i];              f4 b0 = c1[i];
        f4 a1 = c0[i + stride];     f4 b1 = c1[i + stride];
        f4 a2 = c0[i + 2 * stride]; f4 b2 = c1[i + 2 * stride];
        f4 a3 = c0[i + 3 * stride]; f4 b3 = c1[i + 3 * stride];
        __builtin_nontemporal_store(w0 * a0 + w1 * b0, &o[i]);
        __builtin_nontemporal_store(w0 * a1 + w1 * b1, &o[i + stride]);
        __builtin_nontemporal_store(w0 * a2 + w1 * b2, &o[i + 2 * stride]);
        __builtin_nontemporal_store(w0 * a3 + w1 * b3, &o[i + 3 * stride]);
    }
    for (; i < V; i += stride)
        __builtin_nontemporal_store(w0 * c0[i] + w1 * c1[i], &o[i]);
}

extern "C" void kernel_launch(void* const* d_in, const int* in_sizes, int n_in,
                              void* d_out, int out_size, void* d_ws, size_t ws_size,
                              hipStream_t stream) {
    const float* x      = (const float*)d_in[0];   // [B,S,D]
    const float* gate_w = (const float*)d_in[1];   // [E,D]
    const float* cand   = (const float*)d_in[2];   // [E,Nq,D]

    const int E  = NE;
    const int D  = in_sizes[1] / E;          // 768
    const int T  = in_sizes[0] / D;          // 4096
    const int Nq = in_sizes[2] / (E * D);    // 32

    float* outf = (float*)d_out;
    size_t OUT_N = (size_t)T * Nq * D;
    float* out_bal  = outf + OUT_N;
    float* out_imp  = out_bal + 1;
    float* out_load = out_imp + 1;
    float* gate_out = out_load + E;

    float*   prob_sum = (float*)d_ws;                    // 32 B
    int*     cnt      = (int*)((char*)d_ws + 32);        // 32 B
    TokGate* tok      = (TokGate*)((char*)d_ws + 64);    // 16*T B

    hipMemsetAsync(d_ws, 0, 64, stream);

    gate_kernel<<<(T + 3) / 4, 256, 0, stream>>>((const f4*)x, (const f4*)gate_w,
                                                 prob_sum, cnt, tok,
                                                 gate_out, T, D / 4);
    loss_kernel<<<1, 64, 0, stream>>>(prob_sum, cnt, out_bal, out_imp, out_load, T);

    int V = Nq * D / 4;   // 6144 f4 per token
    combine_kernel<<<T, 256, 0, stream>>>((const f4*)cand, tok,
                                          (f4*)d_out, V);
}

// Round 3
// 111.342 us; speedup vs baseline: 1.1112x; 1.0646x over previous
//
#include <hip/hip_runtime.h>

#define NE 8     // experts
#define TOPK 2
#define CHUNK 256   // f4 elements of the [Nq,D] vector per block
#define TPG 64      // tokens per block

typedef float f4 __attribute__((ext_vector_type(4)));

struct TokGate { float w0, w1; int g0, g1; };

// ---------------- Kernel 1: gating ----------------
// One wave (64 lanes) per token. float4 dot products, no runtime register
// indexing (everything static-unrolled -> no scratch).
__global__ void gate_kernel(const f4* __restrict__ x,
                            const f4* __restrict__ gate_w,
                            float* __restrict__ prob_sum,   // [NE] ws (zeroed)
                            int* __restrict__ cnt,          // [NE] ws (zeroed)
                            TokGate* __restrict__ tok,      // [T] ws
                            float* __restrict__ gate_out,   // [T*2] d_out
                            int T, int D4 /* D/4 */) {
    __shared__ float s_psum[NE];
    __shared__ int   s_cnt[NE];
    int tid = threadIdx.x;
    if (tid < NE) { s_psum[tid] = 0.f; s_cnt[tid] = 0; }
    __syncthreads();

    int wave = tid >> 6;
    int lane = tid & 63;
    int t = blockIdx.x * (blockDim.x >> 6) + wave;
    if (t < T) {
        float acc[NE];
#pragma unroll
        for (int e = 0; e < NE; ++e) acc[e] = 0.f;
        const f4* xt = x + (size_t)t * D4;
        for (int d = lane; d < D4; d += 64) {      // coalesced 16B/lane
            f4 xv = xt[d];
#pragma unroll
            for (int e = 0; e < NE; ++e) {
                f4 gw = gate_w[e * D4 + d];        // L1-hit (24 KB total)
                acc[e] = fmaf(xv.x, gw.x,
                         fmaf(xv.y, gw.y,
                         fmaf(xv.z, gw.z,
                         fmaf(xv.w, gw.w, acc[e]))));
            }
        }
#pragma unroll
        for (int e = 0; e < NE; ++e) {
#pragma unroll
            for (int off = 32; off > 0; off >>= 1)
                acc[e] += __shfl_xor(acc[e], off);
        }
        // softmax over 8 (all lanes redundantly)
        float mx = acc[0];
#pragma unroll
        for (int e = 1; e < NE; ++e) mx = fmaxf(mx, acc[e]);
        float p[NE]; float s = 0.f;
#pragma unroll
        for (int e = 0; e < NE; ++e) { p[e] = expf(acc[e] - mx); s += p[e]; }
        float inv = 1.f / s;
#pragma unroll
        for (int e = 0; e < NE; ++e) p[e] *= inv;

        // top-2 with first-index tie-break; static indexing only
        float v0 = -1.f; int g0 = 0;
#pragma unroll
        for (int e = 0; e < NE; ++e)
            if (p[e] > v0) { v0 = p[e]; g0 = e; }
        float v1 = -1.f; int g1 = 0;
#pragma unroll
        for (int e = 0; e < NE; ++e)
            if (e != g0 && p[e] > v1) { v1 = p[e]; g1 = e; }

        float wsum = v0 + v1;
        if (lane == 0) {
            TokGate tg;
            tg.w0 = v0 / wsum; tg.w1 = v1 / wsum;
            tg.g0 = g0; tg.g1 = g1;
            tok[t] = tg;
            gate_out[t * 2 + 0] = (float)g0;
            gate_out[t * 2 + 1] = (float)g1;
            atomicAdd(&s_cnt[g0], 1);
            atomicAdd(&s_cnt[g1], 1);
        }
        // lane e contributes p[e]; select statically (cndmask chain, no scratch)
        float myp = 0.f;
#pragma unroll
        for (int e = 0; e < NE; ++e)
            if (lane == e) myp = p[e];
        if (lane < NE) atomicAdd(&s_psum[lane], myp);
    }
    __syncthreads();
    if (tid < NE) {
        atomicAdd(&prob_sum[tid], s_psum[tid]);
        atomicAdd(&cnt[tid], s_cnt[tid]);
    }
}

// ---------------- Kernel 2: losses ----------------
__global__ void loss_kernel(const float* __restrict__ prob_sum,
                            const int* __restrict__ cnt,
                            float* __restrict__ out_bal,
                            float* __restrict__ out_imp,
                            float* __restrict__ out_load,
                            int T) {
    int lane = threadIdx.x & 63;
    float ps = (lane < NE) ? prob_sum[lane] : 0.f;
    float cv = (lane < NE) ? (float)cnt[lane] : 0.f;
    float sum_ps = ps, sum_c = cv;
#pragma unroll
    for (int off = 4; off >= 1; off >>= 1) {
        sum_ps += __shfl_xor(sum_ps, off);
        sum_c  += __shfl_xor(sum_c, off);
    }
    float mean = sum_ps * (1.f / NE);
    float bal_term = 0.f, dev = 0.f;
    if (lane < NE) {
        bal_term = (ps / (float)T) * (cv / sum_c);
        float d = ps - mean;
        dev = d * d;
    }
#pragma unroll
    for (int off = 4; off >= 1; off >>= 1) {
        bal_term += __shfl_xor(bal_term, off);
        dev      += __shfl_xor(dev, off);
    }
    if (lane == 0) {
        *out_bal = (float)NE * bal_term;
        float var = dev / (float)(NE - 1);     // ddof=1
        *out_imp = var / (mean * mean);
    }
    if (lane < NE) out_load[lane] = cv;        // gate_load as float
}

// ---------------- Kernel 3: combine ----------------
// Block = (chunk c, token-group). Stage chunk c of ALL 8 experts into LDS
// (32 KB) once; loop 64 tokens: 2 ds_read_b128 (uniform expert base ->
// conflict-free) + fma + nt-store. Global cand reads: 786 MB -> ~50 MB.
__global__ void __launch_bounds__(CHUNK)
combine_kernel(const f4* __restrict__ cand,
               const TokGate* __restrict__ tok,
               f4* __restrict__ out,
               int V /* Nq*D/4 */) {
    __shared__ f4 s_cand[NE * CHUNK];
    __shared__ TokGate s_tok[TPG];
    int tid = threadIdx.x;
    int base = blockIdx.x * CHUNK;       // chunk offset within [Nq*D/4]
    int t0 = blockIdx.y * TPG;           // first token of this group

#pragma unroll
    for (int e = 0; e < NE; ++e)
        s_cand[e * CHUNK + tid] = cand[(size_t)e * V + base + tid];
    if (tid < TPG) s_tok[tid] = tok[t0 + tid];
    __syncthreads();

#pragma unroll 4
    for (int k = 0; k < TPG; ++k) {
        TokGate tg = s_tok[k];
        f4 a = s_cand[tg.g0 * CHUNK + tid];
        f4 b = s_cand[tg.g1 * CHUNK + tid];
        f4 r = tg.w0 * a + tg.w1 * b;
        __builtin_nontemporal_store(r, &out[(size_t)(t0 + k) * V + base + tid]);
    }
}

extern "C" void kernel_launch(void* const* d_in, const int* in_sizes, int n_in,
                              void* d_out, int out_size, void* d_ws, size_t ws_size,
                              hipStream_t stream) {
    const float* x      = (const float*)d_in[0];   // [B,S,D]
    const float* gate_w = (const float*)d_in[1];   // [E,D]
    const float* cand   = (const float*)d_in[2];   // [E,Nq,D]

    const int E  = NE;
    const int D  = in_sizes[1] / E;          // 768
    const int T  = in_sizes[0] / D;          // 4096
    const int Nq = in_sizes[2] / (E * D);    // 32

    float* outf = (float*)d_out;
    size_t OUT_N = (size_t)T * Nq * D;
    float* out_bal  = outf + OUT_N;
    float* out_imp  = out_bal + 1;
    float* out_load = out_imp + 1;
    float* gate_out = out_load + E;

    float*   prob_sum = (float*)d_ws;                    // 32 B
    int*     cnt      = (int*)((char*)d_ws + 32);        // 32 B
    TokGate* tok      = (TokGate*)((char*)d_ws + 64);    // 16*T B

    hipMemsetAsync(d_ws, 0, 64, stream);

    gate_kernel<<<(T + 3) / 4, 256, 0, stream>>>((const f4*)x, (const f4*)gate_w,
                                                 prob_sum, cnt, tok,
                                                 gate_out, T, D / 4);
    loss_kernel<<<1, 64, 0, stream>>>(prob_sum, cnt, out_bal, out_imp, out_load, T);

    int V = Nq * D / 4;                      // 6144 f4 per token
    dim3 grid(V / CHUNK, T / TPG);           // (24, 64) = 1536 blocks
    combine_kernel<<<grid, CHUNK, 0, stream>>>((const f4*)cand, tok,
                                               (f4*)d_out, V);
}

// Round 4
// 92.293 us; speedup vs baseline: 1.3406x; 1.2064x over previous
//
#include <hip/hip_runtime.h>

#define NE 8     // experts
#define TOPK 2
#define CHUNK 256   // f4 elements of the [Nq,D] vector per block
#define TPG 64      // tokens per block

typedef float f4 __attribute__((ext_vector_type(4)));

struct TokGate { float w0, w1; int g0, g1; };

// ---------------- Kernel 1: gating ----------------
// One wave per token. Per-block partials written to ws — NO global atomics
// (same-line device atomics from 1024 blocks serialize at the coherence
// point; suspected ~40 us hidden cost).
__global__ void gate_kernel(const f4* __restrict__ x,
                            const f4* __restrict__ gate_w,
                            float* __restrict__ part_psum,  // [nPart*8] ws
                            int* __restrict__ part_cnt,     // [nPart*8] ws
                            TokGate* __restrict__ tok,      // [T] ws
                            float* __restrict__ gate_out,   // [T*2] d_out
                            int T, int D4 /* D/4 */) {
    __shared__ float s_psum[NE];
    __shared__ int   s_cnt[NE];
    int tid = threadIdx.x;
    if (tid < NE) { s_psum[tid] = 0.f; s_cnt[tid] = 0; }
    __syncthreads();

    int wave = tid >> 6;
    int lane = tid & 63;
    int t = blockIdx.x * (blockDim.x >> 6) + wave;
    if (t < T) {
        float acc[NE];
#pragma unroll
        for (int e = 0; e < NE; ++e) acc[e] = 0.f;
        const f4* xt = x + (size_t)t * D4;
        for (int d = lane; d < D4; d += 64) {      // coalesced 16B/lane
            f4 xv = xt[d];
#pragma unroll
            for (int e = 0; e < NE; ++e) {
                f4 gw = gate_w[e * D4 + d];        // L1-hit (24 KB total)
                acc[e] = fmaf(xv.x, gw.x,
                         fmaf(xv.y, gw.y,
                         fmaf(xv.z, gw.z,
                         fmaf(xv.w, gw.w, acc[e]))));
            }
        }
#pragma unroll
        for (int e = 0; e < NE; ++e) {
#pragma unroll
            for (int off = 32; off > 0; off >>= 1)
                acc[e] += __shfl_xor(acc[e], off);
        }
        // softmax over 8 (all lanes redundantly)
        float mx = acc[0];
#pragma unroll
        for (int e = 1; e < NE; ++e) mx = fmaxf(mx, acc[e]);
        float p[NE]; float s = 0.f;
#pragma unroll
        for (int e = 0; e < NE; ++e) { p[e] = expf(acc[e] - mx); s += p[e]; }
        float inv = 1.f / s;
#pragma unroll
        for (int e = 0; e < NE; ++e) p[e] *= inv;

        // top-2 with first-index tie-break; static indexing only
        float v0 = -1.f; int g0 = 0;
#pragma unroll
        for (int e = 0; e < NE; ++e)
            if (p[e] > v0) { v0 = p[e]; g0 = e; }
        float v1 = -1.f; int g1 = 0;
#pragma unroll
        for (int e = 0; e < NE; ++e)
            if (e != g0 && p[e] > v1) { v1 = p[e]; g1 = e; }

        float wsum = v0 + v1;
        if (lane == 0) {
            TokGate tg;
            tg.w0 = v0 / wsum; tg.w1 = v1 / wsum;
            tg.g0 = g0; tg.g1 = g1;
            tok[t] = tg;
            gate_out[t * 2 + 0] = (float)g0;
            gate_out[t * 2 + 1] = (float)g1;
            atomicAdd(&s_cnt[g0], 1);      // LDS atomics only
            atomicAdd(&s_cnt[g1], 1);
        }
        float myp = 0.f;
#pragma unroll
        for (int e = 0; e < NE; ++e)
            if (lane == e) myp = p[e];
        if (lane < NE) atomicAdd(&s_psum[lane], myp);
    }
    __syncthreads();
    if (tid < NE) {
        part_psum[blockIdx.x * NE + tid] = s_psum[tid];
        part_cnt[blockIdx.x * NE + tid]  = s_cnt[tid];
    }
}

// ---------------- Kernel 2: losses (reduce per-block partials) ----------------
__global__ void loss_kernel(const float* __restrict__ part_psum,
                            const int* __restrict__ part_cnt,
                            int nPart,
                            float* __restrict__ out_bal,
                            float* __restrict__ out_imp,
                            float* __restrict__ out_load,
                            int T) {
    __shared__ float sps[4][NE];
    __shared__ float scv[4][NE];
    int tid = threadIdx.x;             // 0..255
    int lane = tid & 63;
    int wave = tid >> 6;
    int e = tid & 7;
    float ps = 0.f, cv = 0.f;
    for (int b = tid >> 3; b < nPart; b += 32) {   // wave reads 256B contiguous
        ps += part_psum[b * NE + e];
        cv += (float)part_cnt[b * NE + e];
    }
    // fold block-stripes within wave (lanes sharing lane&7)
    ps += __shfl_xor(ps, 8);  cv += __shfl_xor(cv, 8);
    ps += __shfl_xor(ps, 16); cv += __shfl_xor(cv, 16);
    ps += __shfl_xor(ps, 32); cv += __shfl_xor(cv, 32);
    if (lane < NE) { sps[wave][lane] = ps; scv[wave][lane] = cv; }
    __syncthreads();
    if (tid < NE) {
        ps = sps[0][tid] + sps[1][tid] + sps[2][tid] + sps[3][tid];
        cv = scv[0][tid] + scv[1][tid] + scv[2][tid] + scv[3][tid];
        float sum_ps = ps, sum_c = cv;
        sum_ps += __shfl_xor(sum_ps, 4); sum_c += __shfl_xor(sum_c, 4);
        sum_ps += __shfl_xor(sum_ps, 2); sum_c += __shfl_xor(sum_c, 2);
        sum_ps += __shfl_xor(sum_ps, 1); sum_c += __shfl_xor(sum_c, 1);
        float mean = sum_ps * (1.f / NE);
        float bal_term = (ps / (float)T) * (cv / sum_c);
        float d = ps - mean;
        float dev = d * d;
        bal_term += __shfl_xor(bal_term, 4); dev += __shfl_xor(dev, 4);
        bal_term += __shfl_xor(bal_term, 2); dev += __shfl_xor(dev, 2);
        bal_term += __shfl_xor(bal_term, 1); dev += __shfl_xor(dev, 1);
        if (tid == 0) {
            *out_bal = (float)NE * bal_term;
            float var = dev * (1.f / (NE - 1));   // ddof=1
            *out_imp = var / (mean * mean);
        }
        out_load[tid] = cv;                        // gate_load as float
    }
}

// ---------------- Kernel 3: combine (unchanged from R3) ----------------
__global__ void __launch_bounds__(CHUNK)
combine_kernel(const f4* __restrict__ cand,
               const TokGate* __restrict__ tok,
               f4* __restrict__ out,
               int V /* Nq*D/4 */) {
    __shared__ f4 s_cand[NE * CHUNK];
    __shared__ TokGate s_tok[TPG];
    int tid = threadIdx.x;
    int base = blockIdx.x * CHUNK;
    int t0 = blockIdx.y * TPG;

#pragma unroll
    for (int e = 0; e < NE; ++e)
        s_cand[e * CHUNK + tid] = cand[(size_t)e * V + base + tid];
    if (tid < TPG) s_tok[tid] = tok[t0 + tid];
    __syncthreads();

#pragma unroll 4
    for (int k = 0; k < TPG; ++k) {
        TokGate tg = s_tok[k];
        f4 a = s_cand[tg.g0 * CHUNK + tid];
        f4 b = s_cand[tg.g1 * CHUNK + tid];
        f4 r = tg.w0 * a + tg.w1 * b;
        __builtin_nontemporal_store(r, &out[(size_t)(t0 + k) * V + base + tid]);
    }
}

extern "C" void kernel_launch(void* const* d_in, const int* in_sizes, int n_in,
                              void* d_out, int out_size, void* d_ws, size_t ws_size,
                              hipStream_t stream) {
    const float* x      = (const float*)d_in[0];   // [B,S,D]
    const float* gate_w = (const float*)d_in[1];   // [E,D]
    const float* cand   = (const float*)d_in[2];   // [E,Nq,D]

    const int E  = NE;
    const int D  = in_sizes[1] / E;          // 768
    const int T  = in_sizes[0] / D;          // 4096
    const int Nq = in_sizes[2] / (E * D);    // 32

    float* outf = (float*)d_out;
    size_t OUT_N = (size_t)T * Nq * D;
    float* out_bal  = outf + OUT_N;
    float* out_imp  = out_bal + 1;
    float* out_load = out_imp + 1;
    float* gate_out = out_load + E;

    int nPart = (T + 3) / 4;                               // 1024 gate blocks
    float*   part_psum = (float*)d_ws;                     // 32 KB
    int*     part_cnt  = (int*)((char*)d_ws + 32768);      // 32 KB
    TokGate* tok       = (TokGate*)((char*)d_ws + 65536);  // 16*T B

    gate_kernel<<<nPart, 256, 0, stream>>>((const f4*)x, (const f4*)gate_w,
                                           part_psum, part_cnt, tok,
                                           gate_out, T, D / 4);

    int V = Nq * D / 4;                      // 6144 f4 per token
    dim3 grid(V / CHUNK, T / TPG);           // (24, 64) = 1536 blocks
    combine_kernel<<<grid, CHUNK, 0, stream>>>((const f4*)cand, tok,
                                               (f4*)d_out, V);

    loss_kernel<<<1, 256, 0, stream>>>(part_psum, part_cnt, nPart,
                                       out_bal, out_imp, out_load, T);
}